// Round 5
// baseline (678.348 us; speedup 1.0000x reference)
//
#include <hip/hip_runtime.h>

#define N_NODES 10000
#define N_EDGES 320000
#define DIM 256
#define ED 64
#define W1_LD 576   // mlp_w1 row stride (2*HID + EDGE_DIM)

// ---------------- CSR build ----------------
__global__ void hist_kernel(const int* __restrict__ dst, int* __restrict__ cnt, int n) {
  int i = blockIdx.x * blockDim.x + threadIdx.x;
  if (i < n) atomicAdd(&cnt[dst[i]], 1);
}

// single-block scan, wave-shuffle based
__global__ void scan_kernel(const int* __restrict__ cnt, int* __restrict__ off,
                            int* __restrict__ cursor, int n) {
  __shared__ int wsum[4];
  __shared__ int carry_s;
  int t = threadIdx.x, lane = t & 63, w = t >> 6;
  if (t == 0) carry_s = 0;
  __syncthreads();
  for (int base = 0; base < n; base += 256) {
    int i = base + t;
    int v = (i < n) ? cnt[i] : 0;
    int sc = v;  // inclusive wave scan
    #pragma unroll
    for (int s = 1; s < 64; s <<= 1) {
      int u = __shfl_up(sc, s, 64);
      if (lane >= s) sc += u;
    }
    if (lane == 63) wsum[w] = sc;
    __syncthreads();
    int woff = 0, tot = 0;
    #pragma unroll
    for (int j = 0; j < 4; ++j) { int s = wsum[j]; if (j < w) woff += s; tot += s; }
    int excl = sc - v + woff + carry_s;
    if (i < n) { off[i] = excl; cursor[i] = excl; }
    __syncthreads();
    if (t == 0) carry_s += tot;
    __syncthreads();
  }
  if (t == 0) off[n] = carry_s;
}

__global__ void scatter_kernel(const int* __restrict__ src, const int* __restrict__ dst,
                               int* __restrict__ cursor, int* __restrict__ csr_src,
                               int* __restrict__ csr_dst, int* __restrict__ csr_eid, int n) {
  int i = blockIdx.x * blockDim.x + threadIdx.x;
  if (i < n) {
    int d = dst[i];
    int p = atomicAdd(&cursor[d], 1);
    csr_src[p] = src[i];
    csr_dst[p] = d;
    csr_eid[p] = i;
  }
}

// ---------------- fused aggregate ----------------
// H[node] = [relu]( mean_{s in nbrs(node)} XP[s][0:256] + bias + XP[node][256:512] )
// 4 nodes/block, one wave per node, lane owns a float4; 8 rows in flight.
template<bool RELU>
__global__ __launch_bounds__(256) void agg_fused_kernel(
    const float* __restrict__ XP,    // [N][512] = lo | hi
    const int* __restrict__ off, const int* __restrict__ csr_src,
    const float* __restrict__ bias,  // [256]
    float* __restrict__ H) {         // [N][256]
  int node = blockIdx.x * 4 + (threadIdx.x >> 6);
  int t4 = (threadIdx.x & 63) * 4;
  int beg = off[node], end = off[node + 1];
  float4 root = *(const float4*)&XP[(size_t)node * 512 + 256 + t4];
  float4 bv = *(const float4*)&bias[t4];
  float sx = 0.f, sy = 0.f, sz = 0.f, sw = 0.f;
  int e = beg;
  for (; e + 7 < end; e += 8) {
    int i0 = csr_src[e],   i1 = csr_src[e+1], i2 = csr_src[e+2], i3 = csr_src[e+3];
    int i4 = csr_src[e+4], i5 = csr_src[e+5], i6 = csr_src[e+6], i7 = csr_src[e+7];
    float4 v0 = *(const float4*)&XP[(size_t)i0 * 512 + t4];
    float4 v1 = *(const float4*)&XP[(size_t)i1 * 512 + t4];
    float4 v2 = *(const float4*)&XP[(size_t)i2 * 512 + t4];
    float4 v3 = *(const float4*)&XP[(size_t)i3 * 512 + t4];
    float4 v4 = *(const float4*)&XP[(size_t)i4 * 512 + t4];
    float4 v5 = *(const float4*)&XP[(size_t)i5 * 512 + t4];
    float4 v6 = *(const float4*)&XP[(size_t)i6 * 512 + t4];
    float4 v7 = *(const float4*)&XP[(size_t)i7 * 512 + t4];
    sx += ((v0.x + v1.x) + (v2.x + v3.x)) + ((v4.x + v5.x) + (v6.x + v7.x));
    sy += ((v0.y + v1.y) + (v2.y + v3.y)) + ((v4.y + v5.y) + (v6.y + v7.y));
    sz += ((v0.z + v1.z) + (v2.z + v3.z)) + ((v4.z + v5.z) + (v6.z + v7.z));
    sw += ((v0.w + v1.w) + (v2.w + v3.w)) + ((v4.w + v5.w) + (v6.w + v7.w));
  }
  for (; e < end; ++e) {
    int s = csr_src[e];
    float4 v = *(const float4*)&XP[(size_t)s * 512 + t4];
    sx += v.x; sy += v.y; sz += v.z; sw += v.w;
  }
  int deg = end - beg;
  float inv = 1.0f / (float)(deg > 0 ? deg : 1);
  float4 r;
  r.x = sx * inv + bv.x + root.x;
  r.y = sy * inv + bv.y + root.y;
  r.z = sz * inv + bv.z + root.z;
  r.w = sw * inv + bv.w + root.w;
  if (RELU) {
    r.x = fmaxf(r.x, 0.f); r.y = fmaxf(r.y, 0.f);
    r.z = fmaxf(r.z, 0.f); r.w = fmaxf(r.w, 0.f);
  }
  *(float4*)&H[(size_t)node * 256 + t4] = r;
}

// ---------------- fp32 GEMM: C[:, 0:512] = A @ [Wlo | Whi]^T (+ bias on lo cols) ----
// A [nrows][256]; Wlo/Whi row-major with leading dim ldw; out col o < split uses
// Wlo row o, o >= split uses Whi row (o-split). C [nrows][512].
// BM=64, BN=64, BK=32; 256 threads; 4x4 accum.
__global__ __launch_bounds__(256) void gemm_kernel(
    const float* __restrict__ A,
    const float* __restrict__ Wlo, const float* __restrict__ Whi,
    const float* __restrict__ bias, float* __restrict__ C,
    int nrows, int ldw, int split) {
  __shared__ float As[32][64];
  __shared__ float Bs[32][64];
  int t = threadIdx.x;
  int tx = t & 15, ty = t >> 4;
  int row0 = blockIdx.x * 64;
  int col0 = blockIdx.y * 64;

  const float* W = Wlo;
  int obase = col0;
  if (col0 >= split) { W = Whi; obase = col0 - split; }

  float acc[4][4];
  #pragma unroll
  for (int i = 0; i < 4; ++i)
    #pragma unroll
    for (int j = 0; j < 4; ++j) acc[i][j] = 0.f;

  for (int kt = 0; kt < 8; ++kt) {
    int kb = kt * 32;
    __syncthreads();
    // stage A tile 64x32
    #pragma unroll
    for (int i = 0; i < 2; ++i) {
      int idx = i * 256 + t;
      int m = idx >> 3;
      int kq = idx & 7;
      int row = row0 + m;
      float4 v = make_float4(0.f, 0.f, 0.f, 0.f);
      if (row < nrows) v = *(const float4*)&A[(size_t)row * 256 + kb + kq * 4];
      As[kq * 4 + 0][m] = v.x; As[kq * 4 + 1][m] = v.y;
      As[kq * 4 + 2][m] = v.z; As[kq * 4 + 3][m] = v.w;
    }
    // stage W tile 64x32
    #pragma unroll
    for (int i = 0; i < 2; ++i) {
      int idx = i * 256 + t;
      int o = idx >> 3;
      int kq = idx & 7;
      float4 v = *(const float4*)&W[(size_t)(obase + o) * ldw + kb + kq * 4];
      Bs[kq * 4 + 0][o] = v.x; Bs[kq * 4 + 1][o] = v.y;
      Bs[kq * 4 + 2][o] = v.z; Bs[kq * 4 + 3][o] = v.w;
    }
    __syncthreads();
    #pragma unroll 8
    for (int k = 0; k < 32; ++k) {
      float4 a0 = *(const float4*)&As[k][ty * 4];
      float4 b0 = *(const float4*)&Bs[k][tx * 4];
      float a[4] = {a0.x, a0.y, a0.z, a0.w};
      float b[4] = {b0.x, b0.y, b0.z, b0.w};
      #pragma unroll
      for (int i = 0; i < 4; ++i)
        #pragma unroll
        for (int j = 0; j < 4; ++j)
          acc[i][j] += a[i] * b[j];
    }
  }
  float4 bv = make_float4(0.f, 0.f, 0.f, 0.f);
  if (bias && col0 < split) bv = *(const float4*)&bias[col0 + tx * 4];
  #pragma unroll
  for (int i = 0; i < 4; ++i) {
    int row = row0 + ty * 4 + i;
    if (row < nrows) {
      float4 o4;
      o4.x = acc[i][0] + bv.x; o4.y = acc[i][1] + bv.y;
      o4.z = acc[i][2] + bv.z; o4.w = acc[i][3] + bv.w;
      *(float4*)&C[(size_t)row * 512 + col0 + tx * 4] = o4;
    }
  }
}

// ---------------- fused edge kernel (CSR-ordered, 128 edges/block) ----------------
// R = ea @ w1c^T in four 64-out chunks; P/Q gathers prefetched one chunk ahead.
// LDS 48 KB, 512 threads -> 3 blocks/CU (24 waves, ~75% occupancy).
#define EB 128
__global__ __launch_bounds__(512, 6) void edge_kernel(
    const float* __restrict__ edge_attr,
    const int* __restrict__ csr_src, const int* __restrict__ csr_dst,
    const int* __restrict__ csr_eid,
    const float* __restrict__ PQ,      // [N][512] = P(+b1) | Q
    const float* __restrict__ mlp_w1,  // [256][576]
    const float* __restrict__ w2,      // [256]
    const float* __restrict__ b2,      // [1]
    float* __restrict__ out) {         // [E]
  __shared__ float w_lds[64][64];      // [k][o] current 64-out chunk of w1c
  __shared__ float ea_lds[64][EB];     // [k][edge]

  int t = threadIdx.x;
  int e0 = blockIdx.x * EB;
  // stage edge_attr transposed via eid indirection
  {
    int e_l = t >> 2, q = t & 3;
    int eid = csr_eid[e0 + e_l];
    const float* ep = &edge_attr[(size_t)eid * ED + q * 16];
    #pragma unroll
    for (int j = 0; j < 4; ++j) {
      float4 v = *(const float4*)&ep[j * 4];
      int k = q * 16 + j * 4;
      ea_lds[k + 0][e_l] = v.x; ea_lds[k + 1][e_l] = v.y;
      ea_lds[k + 2][e_l] = v.z; ea_lds[k + 3][e_l] = v.w;
    }
  }
  int c = t & 15, r = t >> 4;          // c: 16 out-groups, r: 32 edge-groups
  const float* pbase[4];
  const float* qbase[4];
  int eout[4];
  #pragma unroll
  for (int i = 0; i < 4; ++i) {
    int el = e0 + r * 4 + i;
    pbase[i] = &PQ[(size_t)csr_src[el] * 512 + c * 4];
    qbase[i] = &PQ[(size_t)csr_dst[el] * 512 + 256 + c * 4];
    eout[i] = csr_eid[el];
  }
  float logit[4] = {0.f, 0.f, 0.f, 0.f};
  float4 pf[4], qf[4];
  #pragma unroll
  for (int i = 0; i < 4; ++i) {
    pf[i] = *(const float4*)&pbase[i][0];
    qf[i] = *(const float4*)&qbase[i][0];
  }

  for (int chunk = 0; chunk < 4; ++chunk) {
    // stage w chunk: w_lds[k][o] = mlp_w1[(chunk*64+o)*576 + 512 + k]
    #pragma unroll
    for (int i = 0; i < 2; ++i) {
      int idx = i * 512 + t;       // 0..1023
      int o = idx & 63;
      int kq = idx >> 6;           // 0..15
      float4 v = *(const float4*)&mlp_w1[(size_t)(chunk * 64 + o) * W1_LD + 512 + kq * 4];
      w_lds[kq * 4 + 0][o] = v.x; w_lds[kq * 4 + 1][o] = v.y;
      w_lds[kq * 4 + 2][o] = v.z; w_lds[kq * 4 + 3][o] = v.w;
    }
    __syncthreads();               // w (and chunk0: ea) visible
    float acc[4][4];
    #pragma unroll
    for (int i = 0; i < 4; ++i)
      #pragma unroll
      for (int j = 0; j < 4; ++j) acc[i][j] = 0.f;
    #pragma unroll 8
    for (int k = 0; k < 64; ++k) {
      float4 a = *(const float4*)&ea_lds[k][r * 4];
      float4 wv4 = *(const float4*)&w_lds[k][c * 4];
      float av[4] = {a.x, a.y, a.z, a.w};
      float wv[4] = {wv4.x, wv4.y, wv4.z, wv4.w};
      #pragma unroll
      for (int i = 0; i < 4; ++i)
        #pragma unroll
        for (int j = 0; j < 4; ++j)
          acc[i][j] += av[i] * wv[j];
    }
    // epilogue: consume prefetched P/Q, relu, partial dot with w2
    float4 w2v = *(const float4*)&w2[chunk * 64 + c * 4];
    #pragma unroll
    for (int i = 0; i < 4; ++i) {
      float s0 = fmaxf(acc[i][0] + pf[i].x + qf[i].x, 0.f);
      float s1 = fmaxf(acc[i][1] + pf[i].y + qf[i].y, 0.f);
      float s2 = fmaxf(acc[i][2] + pf[i].z + qf[i].z, 0.f);
      float s3 = fmaxf(acc[i][3] + pf[i].w + qf[i].w, 0.f);
      logit[i] += s0 * w2v.x + s1 * w2v.y + s2 * w2v.z + s3 * w2v.w;
    }
    if (chunk < 3) {
      int coff = (chunk + 1) * 64;
      #pragma unroll
      for (int i = 0; i < 4; ++i) {
        pf[i] = *(const float4*)&pbase[i][coff];
        qf[i] = *(const float4*)&qbase[i][coff];
      }
      __syncthreads();             // all waves done reading w_lds before restage
    }
  }
  // reduce over the 16 out-groups (lanes differing in low 4 bits)
  #pragma unroll
  for (int m = 1; m < 16; m <<= 1) {
    #pragma unroll
    for (int i = 0; i < 4; ++i) logit[i] += __shfl_xor(logit[i], m, 64);
  }
  if (c == 0) {
    float bb = b2[0];
    #pragma unroll
    for (int i = 0; i < 4; ++i) out[eout[i]] = logit[i] + bb;
  }
}

// ---------------- launch ----------------
static inline size_t alignup(size_t x) { return (x + 255) & ~(size_t)255; }

extern "C" void kernel_launch(void* const* d_in, const int* in_sizes, int n_in,
                              void* d_out, int out_size, void* d_ws, size_t ws_size,
                              hipStream_t stream) {
  const float* x    = (const float*)d_in[0];
  const float* ea   = (const float*)d_in[1];
  const float* c1wl = (const float*)d_in[2];
  const float* c1bl = (const float*)d_in[3];
  const float* c1wr = (const float*)d_in[4];
  const float* c2wl = (const float*)d_in[5];
  const float* c2bl = (const float*)d_in[6];
  const float* c2wr = (const float*)d_in[7];
  const float* w1   = (const float*)d_in[8];
  const float* b1   = (const float*)d_in[9];
  const float* w2   = (const float*)d_in[10];
  const float* b2   = (const float*)d_in[11];
  const int*   ei   = (const int*)d_in[12];
  const int* src = ei;
  const int* dst = ei + N_EDGES;
  float* out = (float*)d_out;

  char* p = (char*)d_ws;
  size_t o = 0;
  int* cnt      = (int*)(p + o); o += alignup(N_NODES * 4);
  int* off      = (int*)(p + o); o += alignup((N_NODES + 1) * 4);
  int* cursor   = (int*)(p + o); o += alignup(N_NODES * 4);
  int* csr_src  = (int*)(p + o); o += alignup(N_EDGES * 4);
  int* csr_dst  = (int*)(p + o); o += alignup(N_EDGES * 4);
  int* csr_eid  = (int*)(p + o); o += alignup(N_EDGES * 4);
  float* XP     = (float*)(p + o); o += alignup((size_t)N_NODES * 512 * 4);
  float* h      = (float*)(p + o); o += alignup((size_t)N_NODES * 256 * 4);
  float* PQ     = (float*)(p + o); o += alignup((size_t)N_NODES * 512 * 4);

  hipMemsetAsync(cnt, 0, N_NODES * 4, stream);
  hist_kernel<<<(N_EDGES + 255) / 256, 256, 0, stream>>>(dst, cnt, N_EDGES);
  scan_kernel<<<1, 256, 0, stream>>>(cnt, off, cursor, N_NODES);
  scatter_kernel<<<(N_EDGES + 255) / 256, 256, 0, stream>>>(
      src, dst, cursor, csr_src, csr_dst, csr_eid, N_EDGES);

  dim3 ggrid((N_NODES + 63) / 64, 8);

  // conv1: XP = x @ [c1wl | c1wr]^T ; h = relu(mean(XP_lo) + c1bl + XP_hi)
  gemm_kernel<<<ggrid, 256, 0, stream>>>(x, c1wl, c1wr, nullptr, XP, N_NODES, DIM, 256);
  agg_fused_kernel<true><<<N_NODES / 4, 256, 0, stream>>>(XP, off, csr_src, c1bl, h);

  // conv2: XP = h @ [c2wl | c2wr]^T ; h = mean(XP_lo) + c2bl + XP_hi
  gemm_kernel<<<ggrid, 256, 0, stream>>>(h, c2wl, c2wr, nullptr, XP, N_NODES, DIM, 256);
  agg_fused_kernel<false><<<N_NODES / 4, 256, 0, stream>>>(XP, off, csr_src, c2bl, h);

  // PQ: P = h @ w1[:,0:256]^T + b1 | Q = h @ w1[:,256:512]^T
  gemm_kernel<<<ggrid, 256, 0, stream>>>(h, w1, w1 + 256, b1, PQ, N_NODES, W1_LD, 256);

  // fused edge MLP over CSR-ordered edges
  edge_kernel<<<N_EDGES / EB, 512, 0, stream>>>(
      ea, csr_src, csr_dst, csr_eid, PQ, w1, w2, b2, out);
}

// Round 6
// 586.279 us; speedup vs baseline: 1.1570x; 1.1570x over previous
//
#include <hip/hip_runtime.h>

#define N_NODES 10000
#define N_EDGES 320000
#define DIM 256
#define ED 64
#define W1_LD 576   // mlp_w1 row stride (2*HID + EDGE_DIM)

// ---------------- CSR build ----------------
__global__ void hist_kernel(const int* __restrict__ dst, int* __restrict__ cnt, int n) {
  int i = blockIdx.x * blockDim.x + threadIdx.x;
  if (i < n) atomicAdd(&cnt[dst[i]], 1);
}

// single-block scan: thread t serially prefixes elems [t*CH, (t+1)*CH), then a
// cross-thread exclusive scan of per-thread totals. 2 barriers total.
#define SCAN_CH 40   // 256*40 = 10240 >= N_NODES+1
__global__ void scan_kernel(const int* __restrict__ cnt, int* __restrict__ off,
                            int* __restrict__ cursor, int n) {
  __shared__ int wsum[4];
  int t = threadIdx.x, lane = t & 63, w = t >> 6;
  int base = t * SCAN_CH;
  int loc[SCAN_CH];
  int tot = 0;
  #pragma unroll
  for (int j = 0; j < SCAN_CH; ++j) {
    int i = base + j;
    loc[j] = tot;                       // exclusive prefix within chunk
    tot += (i < n) ? cnt[i] : 0;
  }
  // exclusive scan of tot across 256 threads
  int sc = tot;
  #pragma unroll
  for (int s = 1; s < 64; s <<= 1) {
    int u = __shfl_up(sc, s, 64);
    if (lane >= s) sc += u;
  }
  if (lane == 63) wsum[w] = sc;
  __syncthreads();
  int woff = 0;
  #pragma unroll
  for (int j = 0; j < 4; ++j) { int s = wsum[j]; if (j < w) woff += s; }
  int tbase = sc - tot + woff;          // exclusive prefix of this thread's chunk
  #pragma unroll
  for (int j = 0; j < SCAN_CH; ++j) {
    int i = base + j;
    if (i < n) { int v = tbase + loc[j]; off[i] = v; cursor[i] = v; }
    else if (i == n) { off[n] = tbase + loc[j]; }
  }
}

__global__ void scatter_kernel(const int* __restrict__ src, const int* __restrict__ dst,
                               int* __restrict__ cursor, int* __restrict__ csr_src,
                               int* __restrict__ csr_dst, int* __restrict__ csr_eid, int n) {
  int i = blockIdx.x * blockDim.x + threadIdx.x;
  if (i < n) {
    int d = dst[i];
    int p = atomicAdd(&cursor[d], 1);
    csr_src[p] = src[i];
    csr_dst[p] = d;
    csr_eid[p] = i;
  }
}

// ---------------- fused aggregate ----------------
// H[node] = [relu]( mean_{s in nbrs(node)} XP[s][0:256] + bias + XP[node][256:512] )
// 4 nodes/block, one wave per node, lane owns a float4; 8 rows in flight.
template<bool RELU>
__global__ __launch_bounds__(256) void agg_fused_kernel(
    const float* __restrict__ XP,    // [N][512] = lo | hi
    const int* __restrict__ off, const int* __restrict__ csr_src,
    const float* __restrict__ bias,  // [256]
    float* __restrict__ H) {         // [N][256]
  int node = blockIdx.x * 4 + (threadIdx.x >> 6);
  int t4 = (threadIdx.x & 63) * 4;
  int beg = off[node], end = off[node + 1];
  float4 root = *(const float4*)&XP[(size_t)node * 512 + 256 + t4];
  float4 bv = *(const float4*)&bias[t4];
  float sx = 0.f, sy = 0.f, sz = 0.f, sw = 0.f;
  int e = beg;
  for (; e + 7 < end; e += 8) {
    int i0 = csr_src[e],   i1 = csr_src[e+1], i2 = csr_src[e+2], i3 = csr_src[e+3];
    int i4 = csr_src[e+4], i5 = csr_src[e+5], i6 = csr_src[e+6], i7 = csr_src[e+7];
    float4 v0 = *(const float4*)&XP[(size_t)i0 * 512 + t4];
    float4 v1 = *(const float4*)&XP[(size_t)i1 * 512 + t4];
    float4 v2 = *(const float4*)&XP[(size_t)i2 * 512 + t4];
    float4 v3 = *(const float4*)&XP[(size_t)i3 * 512 + t4];
    float4 v4 = *(const float4*)&XP[(size_t)i4 * 512 + t4];
    float4 v5 = *(const float4*)&XP[(size_t)i5 * 512 + t4];
    float4 v6 = *(const float4*)&XP[(size_t)i6 * 512 + t4];
    float4 v7 = *(const float4*)&XP[(size_t)i7 * 512 + t4];
    sx += ((v0.x + v1.x) + (v2.x + v3.x)) + ((v4.x + v5.x) + (v6.x + v7.x));
    sy += ((v0.y + v1.y) + (v2.y + v3.y)) + ((v4.y + v5.y) + (v6.y + v7.y));
    sz += ((v0.z + v1.z) + (v2.z + v3.z)) + ((v4.z + v5.z) + (v6.z + v7.z));
    sw += ((v0.w + v1.w) + (v2.w + v3.w)) + ((v4.w + v5.w) + (v6.w + v7.w));
  }
  for (; e < end; ++e) {
    int s = csr_src[e];
    float4 v = *(const float4*)&XP[(size_t)s * 512 + t4];
    sx += v.x; sy += v.y; sz += v.z; sw += v.w;
  }
  int deg = end - beg;
  float inv = 1.0f / (float)(deg > 0 ? deg : 1);
  float4 r;
  r.x = sx * inv + bv.x + root.x;
  r.y = sy * inv + bv.y + root.y;
  r.z = sz * inv + bv.z + root.z;
  r.w = sw * inv + bv.w + root.w;
  if (RELU) {
    r.x = fmaxf(r.x, 0.f); r.y = fmaxf(r.y, 0.f);
    r.z = fmaxf(r.z, 0.f); r.w = fmaxf(r.w, 0.f);
  }
  *(float4*)&H[(size_t)node * 256 + t4] = r;
}

// ---------------- fp32 GEMM: C[:, 0:512] = A @ [Wlo | Whi]^T (+ bias on lo cols) ----
// A [nrows][256]; Wlo/Whi row-major leading dim ldw; out col o<split uses Wlo row o,
// o>=split uses Whi row (o-split). C [nrows][512].
// BM=128, BN=64, BK=32; 256 threads; 8x4 accum per thread.
__global__ __launch_bounds__(256) void gemm_kernel(
    const float* __restrict__ A,
    const float* __restrict__ Wlo, const float* __restrict__ Whi,
    const float* __restrict__ bias, float* __restrict__ C,
    int nrows, int ldw, int split) {
  __shared__ float As[32][128];
  __shared__ float Bs[32][64];
  int t = threadIdx.x;
  int tx = t & 15, ty = t >> 4;
  int row0 = blockIdx.x * 128;
  int col0 = blockIdx.y * 64;

  const float* W = Wlo;
  int obase = col0;
  if (col0 >= split) { W = Whi; obase = col0 - split; }

  float acc[8][4];
  #pragma unroll
  for (int i = 0; i < 8; ++i)
    #pragma unroll
    for (int j = 0; j < 4; ++j) acc[i][j] = 0.f;

  for (int kt = 0; kt < 8; ++kt) {
    int kb = kt * 32;
    __syncthreads();
    // stage A tile 128x32
    #pragma unroll
    for (int i = 0; i < 4; ++i) {
      int idx = i * 256 + t;       // 0..1023 float4 slots
      int m = idx >> 3;            // 0..127
      int kq = idx & 7;            // 0..7
      int row = row0 + m;
      float4 v = make_float4(0.f, 0.f, 0.f, 0.f);
      if (row < nrows) v = *(const float4*)&A[(size_t)row * 256 + kb + kq * 4];
      As[kq * 4 + 0][m] = v.x; As[kq * 4 + 1][m] = v.y;
      As[kq * 4 + 2][m] = v.z; As[kq * 4 + 3][m] = v.w;
    }
    // stage W tile 64x32
    #pragma unroll
    for (int i = 0; i < 2; ++i) {
      int idx = i * 256 + t;
      int o = idx >> 3;
      int kq = idx & 7;
      float4 v = *(const float4*)&W[(size_t)(obase + o) * ldw + kb + kq * 4];
      Bs[kq * 4 + 0][o] = v.x; Bs[kq * 4 + 1][o] = v.y;
      Bs[kq * 4 + 2][o] = v.z; Bs[kq * 4 + 3][o] = v.w;
    }
    __syncthreads();
    #pragma unroll 8
    for (int k = 0; k < 32; ++k) {
      float4 a0 = *(const float4*)&As[k][ty * 4];
      float4 a1 = *(const float4*)&As[k][ty * 4 + 64];
      float4 b0 = *(const float4*)&Bs[k][tx * 4];
      float a[8] = {a0.x, a0.y, a0.z, a0.w, a1.x, a1.y, a1.z, a1.w};
      float b[4] = {b0.x, b0.y, b0.z, b0.w};
      #pragma unroll
      for (int i = 0; i < 8; ++i)
        #pragma unroll
        for (int j = 0; j < 4; ++j)
          acc[i][j] += a[i] * b[j];
    }
  }
  float4 bv = make_float4(0.f, 0.f, 0.f, 0.f);
  if (bias && col0 < split) bv = *(const float4*)&bias[col0 + tx * 4];
  #pragma unroll
  for (int i = 0; i < 8; ++i) {
    int m = ty * 4 + (i & 3) + (i >> 2) * 64;
    int row = row0 + m;
    if (row < nrows) {
      float4 o4;
      o4.x = acc[i][0] + bv.x; o4.y = acc[i][1] + bv.y;
      o4.z = acc[i][2] + bv.z; o4.w = acc[i][3] + bv.w;
      *(float4*)&C[(size_t)row * 512 + col0 + tx * 4] = o4;
    }
  }
}

// ---------------- fused edge kernel (CSR-ordered; r4-proven config) ----------------
// per block: 64 CSR-consecutive edges (dst-sorted -> Q gather cache-hot).
// R = ea @ w1c^T in four 64-out chunks (w_lds[64][64]), P/Q gathers prefetched
// one chunk ahead. LDS 32.8 KB + launch_bounds(256,4) -> 4 blocks/CU.
#define EB 64
__global__ __launch_bounds__(256, 4) void edge_kernel(
    const float* __restrict__ edge_attr,
    const int* __restrict__ csr_src, const int* __restrict__ csr_dst,
    const int* __restrict__ csr_eid,
    const float* __restrict__ PQ,      // [N][512] = P(+b1) | Q
    const float* __restrict__ mlp_w1,  // [256][576]
    const float* __restrict__ w2,      // [256]
    const float* __restrict__ b2,      // [1]
    float* __restrict__ out) {         // [E]
  __shared__ float w_lds[64][64];      // [k][o] current 64-out chunk of w1c
  __shared__ float ea_lds[64][EB];     // [k][edge]

  int t = threadIdx.x;
  int e0 = blockIdx.x * EB;
  // stage edge_attr transposed via eid indirection
  {
    int e_l = t >> 2, q = t & 3;
    int eid = csr_eid[e0 + e_l];
    const float* ep = &edge_attr[(size_t)eid * ED + q * 16];
    #pragma unroll
    for (int j = 0; j < 4; ++j) {
      float4 v = *(const float4*)&ep[j * 4];
      int k = q * 16 + j * 4;
      ea_lds[k + 0][e_l] = v.x; ea_lds[k + 1][e_l] = v.y;
      ea_lds[k + 2][e_l] = v.z; ea_lds[k + 3][e_l] = v.w;
    }
  }
  int c = t & 15, r = t >> 4;
  const float* pbase[4];
  const float* qbase[4];
  int eout[4];
  #pragma unroll
  for (int i = 0; i < 4; ++i) {
    int el = e0 + r * 4 + i;
    pbase[i] = &PQ[(size_t)csr_src[el] * 512 + c * 4];
    qbase[i] = &PQ[(size_t)csr_dst[el] * 512 + 256 + c * 4];
    eout[i] = csr_eid[el];
  }
  float logit[4] = {0.f, 0.f, 0.f, 0.f};
  float4 pf[4], qf[4];
  #pragma unroll
  for (int i = 0; i < 4; ++i) {
    pf[i] = *(const float4*)&pbase[i][0];
    qf[i] = *(const float4*)&qbase[i][0];
  }

  for (int chunk = 0; chunk < 4; ++chunk) {
    // stage w chunk: w_lds[k][o] = mlp_w1[(chunk*64+o)*576 + 512 + k]
    #pragma unroll
    for (int i = 0; i < 4; ++i) {
      int idx = i * 256 + t;       // 0..1023
      int o = idx & 63;
      int kq = idx >> 6;           // 0..15
      float4 v = *(const float4*)&mlp_w1[(size_t)(chunk * 64 + o) * W1_LD + 512 + kq * 4];
      w_lds[kq * 4 + 0][o] = v.x; w_lds[kq * 4 + 1][o] = v.y;
      w_lds[kq * 4 + 2][o] = v.z; w_lds[kq * 4 + 3][o] = v.w;
    }
    __syncthreads();               // w (and chunk0: ea) visible
    float acc[4][4];
    #pragma unroll
    for (int i = 0; i < 4; ++i)
      #pragma unroll
      for (int j = 0; j < 4; ++j) acc[i][j] = 0.f;
    #pragma unroll 8
    for (int k = 0; k < 64; ++k) {
      float4 a = *(const float4*)&ea_lds[k][r * 4];
      float4 wv4 = *(const float4*)&w_lds[k][c * 4];
      float av[4] = {a.x, a.y, a.z, a.w};
      float wv[4] = {wv4.x, wv4.y, wv4.z, wv4.w};
      #pragma unroll
      for (int i = 0; i < 4; ++i)
        #pragma unroll
        for (int j = 0; j < 4; ++j)
          acc[i][j] += av[i] * wv[j];
    }
    // epilogue: consume prefetched P/Q, relu, partial dot with w2
    float4 w2v = *(const float4*)&w2[chunk * 64 + c * 4];
    #pragma unroll
    for (int i = 0; i < 4; ++i) {
      float s0 = fmaxf(acc[i][0] + pf[i].x + qf[i].x, 0.f);
      float s1 = fmaxf(acc[i][1] + pf[i].y + qf[i].y, 0.f);
      float s2 = fmaxf(acc[i][2] + pf[i].z + qf[i].z, 0.f);
      float s3 = fmaxf(acc[i][3] + pf[i].w + qf[i].w, 0.f);
      logit[i] += s0 * w2v.x + s1 * w2v.y + s2 * w2v.z + s3 * w2v.w;
    }
    if (chunk < 3) {
      int coff = (chunk + 1) * 64;
      #pragma unroll
      for (int i = 0; i < 4; ++i) {
        pf[i] = *(const float4*)&pbase[i][coff];
        qf[i] = *(const float4*)&qbase[i][coff];
      }
      __syncthreads();             // all waves done reading w_lds before restage
    }
  }
  // reduce over the 16 out-groups (lanes differing in low 4 bits)
  #pragma unroll
  for (int m = 1; m < 16; m <<= 1) {
    #pragma unroll
    for (int i = 0; i < 4; ++i) logit[i] += __shfl_xor(logit[i], m, 64);
  }
  if (c == 0) {
    float bb = b2[0];
    #pragma unroll
    for (int i = 0; i < 4; ++i) out[eout[i]] = logit[i] + bb;
  }
}

// ---------------- launch ----------------
static inline size_t alignup(size_t x) { return (x + 255) & ~(size_t)255; }

extern "C" void kernel_launch(void* const* d_in, const int* in_sizes, int n_in,
                              void* d_out, int out_size, void* d_ws, size_t ws_size,
                              hipStream_t stream) {
  const float* x    = (const float*)d_in[0];
  const float* ea   = (const float*)d_in[1];
  const float* c1wl = (const float*)d_in[2];
  const float* c1bl = (const float*)d_in[3];
  const float* c1wr = (const float*)d_in[4];
  const float* c2wl = (const float*)d_in[5];
  const float* c2bl = (const float*)d_in[6];
  const float* c2wr = (const float*)d_in[7];
  const float* w1   = (const float*)d_in[8];
  const float* b1   = (const float*)d_in[9];
  const float* w2   = (const float*)d_in[10];
  const float* b2   = (const float*)d_in[11];
  const int*   ei   = (const int*)d_in[12];
  const int* src = ei;
  const int* dst = ei + N_EDGES;
  float* out = (float*)d_out;

  char* p = (char*)d_ws;
  size_t o = 0;
  int* cnt      = (int*)(p + o); o += alignup(N_NODES * 4);
  int* off      = (int*)(p + o); o += alignup((N_NODES + 1) * 4);
  int* cursor   = (int*)(p + o); o += alignup(N_NODES * 4);
  int* csr_src  = (int*)(p + o); o += alignup(N_EDGES * 4);
  int* csr_dst  = (int*)(p + o); o += alignup(N_EDGES * 4);
  int* csr_eid  = (int*)(p + o); o += alignup(N_EDGES * 4);
  float* XP     = (float*)(p + o); o += alignup((size_t)N_NODES * 512 * 4);
  float* h      = (float*)(p + o); o += alignup((size_t)N_NODES * 256 * 4);
  float* PQ     = (float*)(p + o); o += alignup((size_t)N_NODES * 512 * 4);

  hipMemsetAsync(cnt, 0, N_NODES * 4, stream);
  hist_kernel<<<(N_EDGES + 255) / 256, 256, 0, stream>>>(dst, cnt, N_EDGES);
  scan_kernel<<<1, 256, 0, stream>>>(cnt, off, cursor, N_NODES);
  scatter_kernel<<<(N_EDGES + 255) / 256, 256, 0, stream>>>(
      src, dst, cursor, csr_src, csr_dst, csr_eid, N_EDGES);

  dim3 ggrid((N_NODES + 127) / 128, 8);

  // conv1: XP = x @ [c1wl | c1wr]^T ; h = relu(mean(XP_lo) + c1bl + XP_hi)
  gemm_kernel<<<ggrid, 256, 0, stream>>>(x, c1wl, c1wr, nullptr, XP, N_NODES, DIM, 256);
  agg_fused_kernel<true><<<N_NODES / 4, 256, 0, stream>>>(XP, off, csr_src, c1bl, h);

  // conv2: XP = h @ [c2wl | c2wr]^T ; h = mean(XP_lo) + c2bl + XP_hi
  gemm_kernel<<<ggrid, 256, 0, stream>>>(h, c2wl, c2wr, nullptr, XP, N_NODES, DIM, 256);
  agg_fused_kernel<false><<<N_NODES / 4, 256, 0, stream>>>(XP, off, csr_src, c2bl, h);

  // PQ: P = h @ w1[:,0:256]^T + b1 | Q = h @ w1[:,256:512]^T
  gemm_kernel<<<ggrid, 256, 0, stream>>>(h, w1, w1 + 256, b1, PQ, N_NODES, W1_LD, 256);

  // fused edge MLP over CSR-ordered edges
  edge_kernel<<<N_EDGES / EB, 256, 0, stream>>>(
      ea, csr_src, csr_dst, csr_eid, PQ, w1, w2, b2, out);
}

// Round 7
// 572.244 us; speedup vs baseline: 1.1854x; 1.0245x over previous
//
#include <hip/hip_runtime.h>

#define N_NODES 10000
#define N_EDGES 320000
#define DIM 256
#define ED 64
#define W1_LD 576   // mlp_w1 row stride (2*HID + EDGE_DIM)

// ---------------- CSR build ----------------
__global__ void hist_kernel(const int* __restrict__ dst, int* __restrict__ cnt, int n) {
  int i = blockIdx.x * blockDim.x + threadIdx.x;
  if (i < n) atomicAdd(&cnt[dst[i]], 1);
}

// single-block scan: thread t serially prefixes elems [t*CH, (t+1)*CH), then a
// cross-thread exclusive scan of per-thread totals. 2 barriers total.
#define SCAN_CH 40   // 256*40 = 10240 >= N_NODES+1
__global__ void scan_kernel(const int* __restrict__ cnt, int* __restrict__ off,
                            int* __restrict__ cursor, int n) {
  __shared__ int wsum[4];
  int t = threadIdx.x, lane = t & 63, w = t >> 6;
  int base = t * SCAN_CH;
  int loc[SCAN_CH];
  int tot = 0;
  #pragma unroll
  for (int j = 0; j < SCAN_CH; ++j) {
    int i = base + j;
    loc[j] = tot;                       // exclusive prefix within chunk
    tot += (i < n) ? cnt[i] : 0;
  }
  // exclusive scan of tot across 256 threads
  int sc = tot;
  #pragma unroll
  for (int s = 1; s < 64; s <<= 1) {
    int u = __shfl_up(sc, s, 64);
    if (lane >= s) sc += u;
  }
  if (lane == 63) wsum[w] = sc;
  __syncthreads();
  int woff = 0;
  #pragma unroll
  for (int j = 0; j < 4; ++j) { int s = wsum[j]; if (j < w) woff += s; }
  int tbase = sc - tot + woff;          // exclusive prefix of this thread's chunk
  #pragma unroll
  for (int j = 0; j < SCAN_CH; ++j) {
    int i = base + j;
    if (i < n) { int v = tbase + loc[j]; off[i] = v; cursor[i] = v; }
    else if (i == n) { off[n] = tbase + loc[j]; }
  }
}

__global__ void scatter_kernel(const int* __restrict__ src, const int* __restrict__ dst,
                               int* __restrict__ cursor, int* __restrict__ csr_src,
                               int* __restrict__ csr_dst, int* __restrict__ csr_eid, int n) {
  int i = blockIdx.x * blockDim.x + threadIdx.x;
  if (i < n) {
    int d = dst[i];
    int p = atomicAdd(&cursor[d], 1);
    csr_src[p] = src[i];
    csr_dst[p] = d;
    csr_eid[p] = i;
  }
}

// ---------------- fused aggregate, feature-chunked for L2 residency ----------------
// H[node][f] = [relu]( mean_{s in nbrs(node)} XP[s][f] + bias[f] + XP[node][256+f] )
// Pass structure: chunk (64 floats of the lo half) varies SLOWEST across blockIdx
// so each ~625-block phase gathers from one 10000x256B = 2.5 MB slice -> L2-hot.
// Block: 16 nodes x 16 lanes; lane owns a float4; 8 gather rows in flight.
#define AGG_NB 16
#define AGG_NBLK (N_NODES / AGG_NB)   // 625
template<bool RELU>
__global__ __launch_bounds__(256) void agg_fused_kernel(
    const float* __restrict__ XP,    // [N][512] = lo | hi
    const int* __restrict__ off, const int* __restrict__ csr_src,
    const float* __restrict__ bias,  // [256]
    float* __restrict__ H) {         // [N][256]
  int nodeblk = blockIdx.x % AGG_NBLK;
  int chunk   = blockIdx.x / AGG_NBLK;        // 0..3, slow-varying
  int g = threadIdx.x >> 4;                   // 0..15 node group
  int l = threadIdx.x & 15;                   // 0..15 lane in group
  int node = nodeblk * AGG_NB + g;
  int f = chunk * 64 + l * 4;
  int beg = off[node], end = off[node + 1];
  float4 root = *(const float4*)&XP[(size_t)node * 512 + 256 + f];
  float4 bv = *(const float4*)&bias[f];
  float sx = 0.f, sy = 0.f, sz = 0.f, sw = 0.f;
  int e = beg;
  for (; e + 7 < end; e += 8) {
    int i0 = csr_src[e],   i1 = csr_src[e+1], i2 = csr_src[e+2], i3 = csr_src[e+3];
    int i4 = csr_src[e+4], i5 = csr_src[e+5], i6 = csr_src[e+6], i7 = csr_src[e+7];
    float4 v0 = *(const float4*)&XP[(size_t)i0 * 512 + f];
    float4 v1 = *(const float4*)&XP[(size_t)i1 * 512 + f];
    float4 v2 = *(const float4*)&XP[(size_t)i2 * 512 + f];
    float4 v3 = *(const float4*)&XP[(size_t)i3 * 512 + f];
    float4 v4 = *(const float4*)&XP[(size_t)i4 * 512 + f];
    float4 v5 = *(const float4*)&XP[(size_t)i5 * 512 + f];
    float4 v6 = *(const float4*)&XP[(size_t)i6 * 512 + f];
    float4 v7 = *(const float4*)&XP[(size_t)i7 * 512 + f];
    sx += ((v0.x + v1.x) + (v2.x + v3.x)) + ((v4.x + v5.x) + (v6.x + v7.x));
    sy += ((v0.y + v1.y) + (v2.y + v3.y)) + ((v4.y + v5.y) + (v6.y + v7.y));
    sz += ((v0.z + v1.z) + (v2.z + v3.z)) + ((v4.z + v5.z) + (v6.z + v7.z));
    sw += ((v0.w + v1.w) + (v2.w + v3.w)) + ((v4.w + v5.w) + (v6.w + v7.w));
  }
  for (; e < end; ++e) {
    int s = csr_src[e];
    float4 v = *(const float4*)&XP[(size_t)s * 512 + f];
    sx += v.x; sy += v.y; sz += v.z; sw += v.w;
  }
  int deg = end - beg;
  float inv = 1.0f / (float)(deg > 0 ? deg : 1);
  float4 r;
  r.x = sx * inv + bv.x + root.x;
  r.y = sy * inv + bv.y + root.y;
  r.z = sz * inv + bv.z + root.z;
  r.w = sw * inv + bv.w + root.w;
  if (RELU) {
    r.x = fmaxf(r.x, 0.f); r.y = fmaxf(r.y, 0.f);
    r.z = fmaxf(r.z, 0.f); r.w = fmaxf(r.w, 0.f);
  }
  *(float4*)&H[(size_t)node * 256 + f] = r;
}

// ---------------- fp32 GEMM: C[:, 0:512] = A @ [Wlo | Whi]^T (+ bias on lo cols) ----
// A [nrows][256]; Wlo/Whi row-major leading dim ldw; out col o<split uses Wlo row o,
// o>=split uses Whi row (o-split). C [nrows][512].
// BM=128, BN=64, BK=32; 256 threads; 8x4 accum per thread.
__global__ __launch_bounds__(256) void gemm_kernel(
    const float* __restrict__ A,
    const float* __restrict__ Wlo, const float* __restrict__ Whi,
    const float* __restrict__ bias, float* __restrict__ C,
    int nrows, int ldw, int split) {
  __shared__ float As[32][128];
  __shared__ float Bs[32][64];
  int t = threadIdx.x;
  int tx = t & 15, ty = t >> 4;
  int row0 = blockIdx.x * 128;
  int col0 = blockIdx.y * 64;

  const float* W = Wlo;
  int obase = col0;
  if (col0 >= split) { W = Whi; obase = col0 - split; }

  float acc[8][4];
  #pragma unroll
  for (int i = 0; i < 8; ++i)
    #pragma unroll
    for (int j = 0; j < 4; ++j) acc[i][j] = 0.f;

  for (int kt = 0; kt < 8; ++kt) {
    int kb = kt * 32;
    __syncthreads();
    // stage A tile 128x32
    #pragma unroll
    for (int i = 0; i < 4; ++i) {
      int idx = i * 256 + t;       // 0..1023 float4 slots
      int m = idx >> 3;            // 0..127
      int kq = idx & 7;            // 0..7
      int row = row0 + m;
      float4 v = make_float4(0.f, 0.f, 0.f, 0.f);
      if (row < nrows) v = *(const float4*)&A[(size_t)row * 256 + kb + kq * 4];
      As[kq * 4 + 0][m] = v.x; As[kq * 4 + 1][m] = v.y;
      As[kq * 4 + 2][m] = v.z; As[kq * 4 + 3][m] = v.w;
    }
    // stage W tile 64x32
    #pragma unroll
    for (int i = 0; i < 2; ++i) {
      int idx = i * 256 + t;
      int o = idx >> 3;
      int kq = idx & 7;
      float4 v = *(const float4*)&W[(size_t)(obase + o) * ldw + kb + kq * 4];
      Bs[kq * 4 + 0][o] = v.x; Bs[kq * 4 + 1][o] = v.y;
      Bs[kq * 4 + 2][o] = v.z; Bs[kq * 4 + 3][o] = v.w;
    }
    __syncthreads();
    #pragma unroll 8
    for (int k = 0; k < 32; ++k) {
      float4 a0 = *(const float4*)&As[k][ty * 4];
      float4 a1 = *(const float4*)&As[k][ty * 4 + 64];
      float4 b0 = *(const float4*)&Bs[k][tx * 4];
      float a[8] = {a0.x, a0.y, a0.z, a0.w, a1.x, a1.y, a1.z, a1.w};
      float b[4] = {b0.x, b0.y, b0.z, b0.w};
      #pragma unroll
      for (int i = 0; i < 8; ++i)
        #pragma unroll
        for (int j = 0; j < 4; ++j)
          acc[i][j] += a[i] * b[j];
    }
  }
  float4 bv = make_float4(0.f, 0.f, 0.f, 0.f);
  if (bias && col0 < split) bv = *(const float4*)&bias[col0 + tx * 4];
  #pragma unroll
  for (int i = 0; i < 8; ++i) {
    int m = ty * 4 + (i & 3) + (i >> 2) * 64;
    int row = row0 + m;
    if (row < nrows) {
      float4 o4;
      o4.x = acc[i][0] + bv.x; o4.y = acc[i][1] + bv.y;
      o4.z = acc[i][2] + bv.z; o4.w = acc[i][3] + bv.w;
      *(float4*)&C[(size_t)row * 512 + col0 + tx * 4] = o4;
    }
  }
}

// ---------------- fused edge kernel (CSR-ordered; r4-proven config) ----------------
// per block: 64 CSR-consecutive edges (dst-sorted -> Q gather cache-hot).
// R = ea @ w1c^T in four 64-out chunks (w_lds[64][64]), P/Q gathers prefetched
// one chunk ahead. LDS 32.8 KB + launch_bounds(256,4) -> 4 blocks/CU.
#define EB 64
__global__ __launch_bounds__(256, 4) void edge_kernel(
    const float* __restrict__ edge_attr,
    const int* __restrict__ csr_src, const int* __restrict__ csr_dst,
    const int* __restrict__ csr_eid,
    const float* __restrict__ PQ,      // [N][512] = P(+b1) | Q
    const float* __restrict__ mlp_w1,  // [256][576]
    const float* __restrict__ w2,      // [256]
    const float* __restrict__ b2,      // [1]
    float* __restrict__ out) {         // [E]
  __shared__ float w_lds[64][64];      // [k][o] current 64-out chunk of w1c
  __shared__ float ea_lds[64][EB];     // [k][edge]

  int t = threadIdx.x;
  int e0 = blockIdx.x * EB;
  // stage edge_attr transposed via eid indirection
  {
    int e_l = t >> 2, q = t & 3;
    int eid = csr_eid[e0 + e_l];
    const float* ep = &edge_attr[(size_t)eid * ED + q * 16];
    #pragma unroll
    for (int j = 0; j < 4; ++j) {
      float4 v = *(const float4*)&ep[j * 4];
      int k = q * 16 + j * 4;
      ea_lds[k + 0][e_l] = v.x; ea_lds[k + 1][e_l] = v.y;
      ea_lds[k + 2][e_l] = v.z; ea_lds[k + 3][e_l] = v.w;
    }
  }
  int c = t & 15, r = t >> 4;
  const float* pbase[4];
  const float* qbase[4];
  int eout[4];
  #pragma unroll
  for (int i = 0; i < 4; ++i) {
    int el = e0 + r * 4 + i;
    pbase[i] = &PQ[(size_t)csr_src[el] * 512 + c * 4];
    qbase[i] = &PQ[(size_t)csr_dst[el] * 512 + 256 + c * 4];
    eout[i] = csr_eid[el];
  }
  float logit[4] = {0.f, 0.f, 0.f, 0.f};
  float4 pf[4], qf[4];
  #pragma unroll
  for (int i = 0; i < 4; ++i) {
    pf[i] = *(const float4*)&pbase[i][0];
    qf[i] = *(const float4*)&qbase[i][0];
  }

  for (int chunk = 0; chunk < 4; ++chunk) {
    // stage w chunk: w_lds[k][o] = mlp_w1[(chunk*64+o)*576 + 512 + k]
    #pragma unroll
    for (int i = 0; i < 4; ++i) {
      int idx = i * 256 + t;       // 0..1023
      int o = idx & 63;
      int kq = idx >> 6;           // 0..15
      float4 v = *(const float4*)&mlp_w1[(size_t)(chunk * 64 + o) * W1_LD + 512 + kq * 4];
      w_lds[kq * 4 + 0][o] = v.x; w_lds[kq * 4 + 1][o] = v.y;
      w_lds[kq * 4 + 2][o] = v.z; w_lds[kq * 4 + 3][o] = v.w;
    }
    __syncthreads();               // w (and chunk0: ea) visible
    float acc[4][4];
    #pragma unroll
    for (int i = 0; i < 4; ++i)
      #pragma unroll
      for (int j = 0; j < 4; ++j) acc[i][j] = 0.f;
    #pragma unroll 8
    for (int k = 0; k < 64; ++k) {
      float4 a = *(const float4*)&ea_lds[k][r * 4];
      float4 wv4 = *(const float4*)&w_lds[k][c * 4];
      float av[4] = {a.x, a.y, a.z, a.w};
      float wv[4] = {wv4.x, wv4.y, wv4.z, wv4.w};
      #pragma unroll
      for (int i = 0; i < 4; ++i)
        #pragma unroll
        for (int j = 0; j < 4; ++j)
          acc[i][j] += av[i] * wv[j];
    }
    // epilogue: consume prefetched P/Q, relu, partial dot with w2
    float4 w2v = *(const float4*)&w2[chunk * 64 + c * 4];
    #pragma unroll
    for (int i = 0; i < 4; ++i) {
      float s0 = fmaxf(acc[i][0] + pf[i].x + qf[i].x, 0.f);
      float s1 = fmaxf(acc[i][1] + pf[i].y + qf[i].y, 0.f);
      float s2 = fmaxf(acc[i][2] + pf[i].z + qf[i].z, 0.f);
      float s3 = fmaxf(acc[i][3] + pf[i].w + qf[i].w, 0.f);
      logit[i] += s0 * w2v.x + s1 * w2v.y + s2 * w2v.z + s3 * w2v.w;
    }
    if (chunk < 3) {
      int coff = (chunk + 1) * 64;
      #pragma unroll
      for (int i = 0; i < 4; ++i) {
        pf[i] = *(const float4*)&pbase[i][coff];
        qf[i] = *(const float4*)&qbase[i][coff];
      }
      __syncthreads();             // all waves done reading w_lds before restage
    }
  }
  // reduce over the 16 out-groups (lanes differing in low 4 bits)
  #pragma unroll
  for (int m = 1; m < 16; m <<= 1) {
    #pragma unroll
    for (int i = 0; i < 4; ++i) logit[i] += __shfl_xor(logit[i], m, 64);
  }
  if (c == 0) {
    float bb = b2[0];
    #pragma unroll
    for (int i = 0; i < 4; ++i) out[eout[i]] = logit[i] + bb;
  }
}

// ---------------- launch ----------------
static inline size_t alignup(size_t x) { return (x + 255) & ~(size_t)255; }

extern "C" void kernel_launch(void* const* d_in, const int* in_sizes, int n_in,
                              void* d_out, int out_size, void* d_ws, size_t ws_size,
                              hipStream_t stream) {
  const float* x    = (const float*)d_in[0];
  const float* ea   = (const float*)d_in[1];
  const float* c1wl = (const float*)d_in[2];
  const float* c1bl = (const float*)d_in[3];
  const float* c1wr = (const float*)d_in[4];
  const float* c2wl = (const float*)d_in[5];
  const float* c2bl = (const float*)d_in[6];
  const float* c2wr = (const float*)d_in[7];
  const float* w1   = (const float*)d_in[8];
  const float* b1   = (const float*)d_in[9];
  const float* w2   = (const float*)d_in[10];
  const float* b2   = (const float*)d_in[11];
  const int*   ei   = (const int*)d_in[12];
  const int* src = ei;
  const int* dst = ei + N_EDGES;
  float* out = (float*)d_out;

  char* p = (char*)d_ws;
  size_t o = 0;
  int* cnt      = (int*)(p + o); o += alignup(N_NODES * 4);
  int* off      = (int*)(p + o); o += alignup((N_NODES + 1) * 4);
  int* cursor   = (int*)(p + o); o += alignup(N_NODES * 4);
  int* csr_src  = (int*)(p + o); o += alignup(N_EDGES * 4);
  int* csr_dst  = (int*)(p + o); o += alignup(N_EDGES * 4);
  int* csr_eid  = (int*)(p + o); o += alignup(N_EDGES * 4);
  float* XP     = (float*)(p + o); o += alignup((size_t)N_NODES * 512 * 4);
  float* h      = (float*)(p + o); o += alignup((size_t)N_NODES * 256 * 4);
  float* PQ     = (float*)(p + o); o += alignup((size_t)N_NODES * 512 * 4);

  hipMemsetAsync(cnt, 0, N_NODES * 4, stream);
  hist_kernel<<<(N_EDGES + 255) / 256, 256, 0, stream>>>(dst, cnt, N_EDGES);
  scan_kernel<<<1, 256, 0, stream>>>(cnt, off, cursor, N_NODES);
  scatter_kernel<<<(N_EDGES + 255) / 256, 256, 0, stream>>>(
      src, dst, cursor, csr_src, csr_dst, csr_eid, N_EDGES);

  dim3 ggrid((N_NODES + 127) / 128, 8);

  // conv1: XP = x @ [c1wl | c1wr]^T ; h = relu(mean(XP_lo) + c1bl + XP_hi)
  gemm_kernel<<<ggrid, 256, 0, stream>>>(x, c1wl, c1wr, nullptr, XP, N_NODES, DIM, 256);
  agg_fused_kernel<true><<<AGG_NBLK * 4, 256, 0, stream>>>(XP, off, csr_src, c1bl, h);

  // conv2: XP = h @ [c2wl | c2wr]^T ; h = mean(XP_lo) + c2bl + XP_hi
  gemm_kernel<<<ggrid, 256, 0, stream>>>(h, c2wl, c2wr, nullptr, XP, N_NODES, DIM, 256);
  agg_fused_kernel<false><<<AGG_NBLK * 4, 256, 0, stream>>>(XP, off, csr_src, c2bl, h);

  // PQ: P = h @ w1[:,0:256]^T + b1 | Q = h @ w1[:,256:512]^T
  gemm_kernel<<<ggrid, 256, 0, stream>>>(h, w1, w1 + 256, b1, PQ, N_NODES, W1_LD, 256);

  // fused edge MLP over CSR-ordered edges
  edge_kernel<<<N_EDGES / EB, 256, 0, stream>>>(
      ea, csr_src, csr_dst, csr_eid, PQ, w1, w2, b2, out);
}